// Round 2
// baseline (1291.181 us; speedup 1.0000x reference)
//
#include <hip/hip_runtime.h>
#include <math.h>

// Problem constants (fixed by reference setup_inputs)
#define BB    8
#define CC    256      // channels
#define RR    256      // token bank size
#define HWV   16384    // H*W
#define NPIX  131072   // B*H*W
#define COUT  256
#define TILE  32       // pixels per block

typedef float f4 __attribute__((ext_vector_type(4)));

// ---------------- kM: M[o][r] = sum_c W2[o][c] * T[r][c]  (W2 = w_out[:,256:512])
__global__ void kM(const float* __restrict__ w_out, const float* __restrict__ t_items,
                   float* __restrict__ M) {
    __shared__ float wl[CC];
    const int o = blockIdx.x;
    const int t = threadIdx.x;           // 256 threads, t == r
    wl[t] = w_out[o * 512 + 256 + t];
    __syncthreads();
    const f4* tr = (const f4*)(t_items + t * CC);
    float acc = 0.0f;
    #pragma unroll
    for (int c4 = 0; c4 < 64; c4++) {
        f4 v = tr[c4];
        acc = fmaf(wl[c4*4+0], v[0], acc);
        acc = fmaf(wl[c4*4+1], v[1], acc);
        acc = fmaf(wl[c4*4+2], v[2], acc);
        acc = fmaf(wl[c4*4+3], v[3], acc);
    }
    M[o * RR + t] = acc;
}

// ---------------- k0: zero the BN accumulators (512 floats)
__global__ void k0(float* __restrict__ g) {
    g[blockIdx.x * 256 + threadIdx.x] = 0.0f;
}

// ---------------- k1: fused normalize -> cue -> softmax -> y = W1@qhat + M@attn
__launch_bounds__(256, 2)
__global__ void k1(const float* __restrict__ query, const float* __restrict__ t_items,
                   const float* __restrict__ w_out, const float* __restrict__ Mmat,
                   float* __restrict__ out, float* __restrict__ gsum, float* __restrict__ gss) {
    __shared__ float qs[CC][TILE];   // 32 KB — normalized query tile [c][p]
    __shared__ float at[RR][TILE];   // 32 KB — cue / attn tile [r][p]
    __shared__ float red[8][TILE];
    __shared__ float pscale[TILE];
    __shared__ float smax[TILE];
    __shared__ float ssumi[TILE];

    const int t    = threadIdx.x;
    const int pix0 = blockIdx.x * TILE;
    const int b    = pix0 >> 14;
    const int hw0  = pix0 & (HWV - 1);
    const int qbase = ((b * CC) << 14) + hw0;

    // ---- Stage A: load query tile (coalesced float4), compute L2 scale, normalize in LDS
    {
        const f4* qg = (const f4*)(query + qbase);
        #pragma unroll
        for (int k = 0; k < 8; k++) {
            int f  = t + k * 256;          // float4 id: 2048 total
            int c  = f >> 3;
            int p4 = f & 7;
            f4 v = qg[c * (HWV / 4) + p4];
            *((f4*)&qs[c][p4 * 4]) = v;
        }
    }
    __syncthreads();
    {
        int p = t & 31, g = t >> 5;
        float s = 0.0f;
        #pragma unroll
        for (int cc = 0; cc < 32; cc++) { float v = qs[g * 32 + cc][p]; s = fmaf(v, v, s); }
        red[g][p] = s;
        __syncthreads();
        if (t < 32) {
            float tot = 0.0f;
            #pragma unroll
            for (int g2 = 0; g2 < 8; g2++) tot += red[g2][t];
            pscale[t] = 1.0f / fmaxf(sqrtf(tot), 1e-12f);
        }
        __syncthreads();
        #pragma unroll
        for (int k = 0; k < 8; k++) {
            int f  = t + k * 256;
            int c  = f >> 3;
            int p4 = f & 7;
            f4 v = *((f4*)&qs[c][p4 * 4]);
            v[0] *= pscale[p4 * 4 + 0];
            v[1] *= pscale[p4 * 4 + 1];
            v[2] *= pscale[p4 * 4 + 2];
            v[3] *= pscale[p4 * 4 + 3];
            *((f4*)&qs[c][p4 * 4]) = v;
        }
    }
    __syncthreads();

    const int pg = t & 7;        // pixel group
    const int p0 = pg * 4;
    const int gg = t >> 3;       // 0..31: row group (r or o)
    const int r0 = gg * 8;

    // ---- Stage B: cue[r][p] = sum_c T[r][c] * qhat[c][p]  (8 rows x 4 pixels per thread)
    {
        f4 acc[8] = {f4(0.f),f4(0.f),f4(0.f),f4(0.f),f4(0.f),f4(0.f),f4(0.f),f4(0.f)};
        for (int c4 = 0; c4 < 64; c4++) {
            int c = c4 * 4;
            f4 qv0 = *((const f4*)&qs[c + 0][p0]);
            f4 qv1 = *((const f4*)&qs[c + 1][p0]);
            f4 qv2 = *((const f4*)&qs[c + 2][p0]);
            f4 qv3 = *((const f4*)&qs[c + 3][p0]);
            #pragma unroll
            for (int i = 0; i < 8; i++) {
                f4 tv = *((const f4*)(t_items + (r0 + i) * CC + c));
                acc[i] += tv[0] * qv0;
                acc[i] += tv[1] * qv1;
                acc[i] += tv[2] * qv2;
                acc[i] += tv[3] * qv3;
            }
        }
        #pragma unroll
        for (int i = 0; i < 8; i++) *((f4*)&at[r0 + i][p0]) = acc[i];
    }
    __syncthreads();

    // ---- Stage B': softmax over r (per pixel), normalized attn left in at[][]
    {
        int p = t & 31, g = t >> 5;
        float m = -1e30f;
        #pragma unroll
        for (int cc = 0; cc < 32; cc++) m = fmaxf(m, at[g * 32 + cc][p]);
        red[g][p] = m;
        __syncthreads();
        if (t < 32) {
            float mm = red[0][t];
            #pragma unroll
            for (int g2 = 1; g2 < 8; g2++) mm = fmaxf(mm, red[g2][t]);
            smax[t] = mm;
        }
        __syncthreads();
        float s = 0.0f;
        #pragma unroll
        for (int cc = 0; cc < 32; cc++) {
            float e = expf(at[g * 32 + cc][p] - smax[p]);
            at[g * 32 + cc][p] = e;
            s += e;
        }
        red[g][p] = s;
        __syncthreads();
        if (t < 32) {
            float tot = 0.0f;
            #pragma unroll
            for (int g2 = 0; g2 < 8; g2++) tot += red[g2][t];
            ssumi[t] = 1.0f / tot;
        }
        __syncthreads();
        #pragma unroll
        for (int k = 0; k < 8; k++) {
            int f  = t + k * 256;
            int rr = f >> 3;
            int p4 = f & 7;
            f4 v = *((f4*)&at[rr][p4 * 4]);
            v[0] *= ssumi[p4 * 4 + 0];
            v[1] *= ssumi[p4 * 4 + 1];
            v[2] *= ssumi[p4 * 4 + 2];
            v[3] *= ssumi[p4 * 4 + 3];
            *((f4*)&at[rr][p4 * 4]) = v;
        }
    }
    __syncthreads();

    // ---- Stage C: y[o][p] = sum_c W1[o][c]*qhat[c][p] + sum_r M[o][r]*attn[r][p]
    {
        const int o0 = r0;
        f4 acc[8] = {f4(0.f),f4(0.f),f4(0.f),f4(0.f),f4(0.f),f4(0.f),f4(0.f),f4(0.f)};
        for (int c4 = 0; c4 < 64; c4++) {
            int c = c4 * 4;
            f4 qv0 = *((const f4*)&qs[c + 0][p0]);
            f4 qv1 = *((const f4*)&qs[c + 1][p0]);
            f4 qv2 = *((const f4*)&qs[c + 2][p0]);
            f4 qv3 = *((const f4*)&qs[c + 3][p0]);
            #pragma unroll
            for (int i = 0; i < 8; i++) {
                f4 wv = *((const f4*)(w_out + (o0 + i) * 512 + c));
                acc[i] += wv[0] * qv0;
                acc[i] += wv[1] * qv1;
                acc[i] += wv[2] * qv2;
                acc[i] += wv[3] * qv3;
            }
        }
        for (int r4 = 0; r4 < 64; r4++) {
            int r = r4 * 4;
            f4 av0 = *((const f4*)&at[r + 0][p0]);
            f4 av1 = *((const f4*)&at[r + 1][p0]);
            f4 av2 = *((const f4*)&at[r + 2][p0]);
            f4 av3 = *((const f4*)&at[r + 3][p0]);
            #pragma unroll
            for (int i = 0; i < 8; i++) {
                f4 mv = *((const f4*)(Mmat + (o0 + i) * RR + r));
                acc[i] += mv[0] * av0;
                acc[i] += mv[1] * av1;
                acc[i] += mv[2] * av2;
                acc[i] += mv[3] * av3;
            }
        }
        // store y (pre-BN) into d_out + per-channel partial sums for BN
        const int obase = ((b * COUT) << 14) + hw0;
        float psum[8], psq[8];
        #pragma unroll
        for (int i = 0; i < 8; i++) {
            f4 v = acc[i];
            *((f4*)(out + obase + (o0 + i) * HWV + p0)) = v;
            psum[i] = (v[0] + v[1]) + (v[2] + v[3]);
            psq[i]  = fmaf(v[0], v[0], fmaf(v[1], v[1], fmaf(v[2], v[2], v[3] * v[3])));
        }
        #pragma unroll
        for (int off = 1; off < 8; off <<= 1) {
            #pragma unroll
            for (int i = 0; i < 8; i++) {
                psum[i] += __shfl_xor(psum[i], off);
                psq[i]  += __shfl_xor(psq[i], off);
            }
        }
        if (pg == 0) {
            #pragma unroll
            for (int i = 0; i < 8; i++) {
                atomicAdd(&gsum[o0 + i], psum[i]);
                atomicAdd(&gss[o0 + i], psq[i]);
            }
        }
    }
}

// ---------------- k2: finalize BN affine params
__global__ void k2(const float* __restrict__ gsum, const float* __restrict__ gss,
                   const float* __restrict__ gamma, const float* __restrict__ beta,
                   float* __restrict__ params) {
    const int o = threadIdx.x;   // 256
    const float inv_n = 1.0f / (float)NPIX;
    float mean = gsum[o] * inv_n;
    float var  = gss[o] * inv_n - mean * mean;
    float sc   = gamma[o] / sqrtf(var + 1e-5f);
    params[o]        = sc;
    params[256 + o]  = beta[o] - mean * sc;
}

// ---------------- k3: apply BN + ReLU in place on d_out
__global__ void k3(float* __restrict__ out, const float* __restrict__ params) {
    const int idx = blockIdx.x * 256 + threadIdx.x;      // float4 index, total 8388608
    const int o = (idx >> 12) & 255;                     // (idx*4) >> 14
    f4* o4 = (f4*)out;
    f4 v = o4[idx];
    float sc = params[o], bi = params[256 + o];
    v[0] = fmaxf(fmaf(v[0], sc, bi), 0.0f);
    v[1] = fmaxf(fmaf(v[1], sc, bi), 0.0f);
    v[2] = fmaxf(fmaf(v[2], sc, bi), 0.0f);
    v[3] = fmaxf(fmaf(v[3], sc, bi), 0.0f);
    o4[idx] = v;
}

extern "C" void kernel_launch(void* const* d_in, const int* in_sizes, int n_in,
                              void* d_out, int out_size, void* d_ws, size_t ws_size,
                              hipStream_t stream) {
    const float* query   = (const float*)d_in[0];
    const float* t_items = (const float*)d_in[1];
    const float* w_out   = (const float*)d_in[2];
    const float* gamma   = (const float*)d_in[3];
    const float* beta    = (const float*)d_in[4];
    float* out = (float*)d_out;
    float* ws  = (float*)d_ws;

    // ws layout (floats): M[65536] | gsum[256] | gss[256] | params[512]
    float* Mmat   = ws;
    float* gsum   = ws + 65536;
    float* gss    = ws + 65536 + 256;
    float* params = ws + 65536 + 512;

    k0<<<2, 256, 0, stream>>>(gsum);                                 // zero gsum+gss (contiguous 512)
    kM<<<256, 256, 0, stream>>>(w_out, t_items, Mmat);
    k1<<<NPIX / TILE, 256, 0, stream>>>(query, t_items, w_out, Mmat, out, gsum, gss);
    k2<<<1, 256, 0, stream>>>(gsum, gss, gamma, beta, params);
    k3<<<NPIX * COUT / 4 / 256, 256, 0, stream>>>(out, params);
}